// Round 2
// baseline (963.573 us; speedup 1.0000x reference)
//
#include <hip/hip_runtime.h>

// B=4,H=16 (BH=64), S=1024, D=64, fp32 in/out.
//   M2[u][d]   = sum_t mask[u][t] K[t][d]          (reassociated mask GEMM)
//   logits[s,u]= scale * sum_d Q[s][d] M2[u][d]
//   attn       = softmax(logits); context = attn @ V
// All big GEMMs run as split-fp32 bf16 MFMA: x = hi(bf16) + lo(bf16),
// a*b ~= ah*bh + ah*bl + al*bh  (3 MFMAs, ~2^-16 relative error).

#define S 1024
#define D 64
#define BH 64
#define SCALE 0.125f

typedef short s16x8 __attribute__((ext_vector_type(8)));
typedef float f32x4 __attribute__((ext_vector_type(4)));
typedef unsigned short u16;

__device__ __forceinline__ void split2(float x, u16& h, u16& l) {
    unsigned u = __float_as_uint(x);
    h = (u16)(u >> 16);                       // truncated hi bf16
    float xh = __uint_as_float(u & 0xFFFF0000u);
    l = (u16)(__float_as_uint(x - xh) >> 16); // lo captures the residual
}

// ---------------------------------------------------------------------------
// K0: split K and V to bf16 hi/lo, transposed to [bh][d][t] (B-operand layout)
// ---------------------------------------------------------------------------
__global__ __launch_bounds__(256) void split_transpose(
        const float* __restrict__ Kin, const float* __restrict__ Vin,
        u16* __restrict__ Khi, u16* __restrict__ Klo,
        u16* __restrict__ Vhi, u16* __restrict__ Vlo) {
    const float* X = blockIdx.z ? Vin : Kin;
    u16* Xhi = blockIdx.z ? Vhi : Khi;
    u16* Xlo = blockIdx.z ? Vlo : Klo;
    const int bh = blockIdx.y, t0 = blockIdx.x * 64, tid = threadIdx.x;
    __shared__ u16 Th[64 * 72], Tl[64 * 72];
    {
        const int tr = tid >> 2, ds = (tid & 3) * 16;
        const float* src = X + ((size_t)bh * S + t0 + tr) * D + ds;
        u16 h[16], l[16];
#pragma unroll
        for (int j = 0; j < 4; j++) {
            float4 v = *(const float4*)(src + j * 4);
            split2(v.x, h[4 * j + 0], l[4 * j + 0]);
            split2(v.y, h[4 * j + 1], l[4 * j + 1]);
            split2(v.z, h[4 * j + 2], l[4 * j + 2]);
            split2(v.w, h[4 * j + 3], l[4 * j + 3]);
        }
#pragma unroll
        for (int hf = 0; hf < 2; hf++) {
            uint4 ph, pl;
            ph.x = h[8*hf+0] | ((unsigned)h[8*hf+1] << 16);
            ph.y = h[8*hf+2] | ((unsigned)h[8*hf+3] << 16);
            ph.z = h[8*hf+4] | ((unsigned)h[8*hf+5] << 16);
            ph.w = h[8*hf+6] | ((unsigned)h[8*hf+7] << 16);
            pl.x = l[8*hf+0] | ((unsigned)l[8*hf+1] << 16);
            pl.y = l[8*hf+2] | ((unsigned)l[8*hf+3] << 16);
            pl.z = l[8*hf+4] | ((unsigned)l[8*hf+5] << 16);
            pl.w = l[8*hf+6] | ((unsigned)l[8*hf+7] << 16);
            *(uint4*)&Th[tr * 72 + ds + hf * 8] = ph;
            *(uint4*)&Tl[tr * 72 + ds + hf * 8] = pl;
        }
    }
    __syncthreads();
    {
        const int d = tid >> 2, ts = (tid & 3) * 16;
        u16 h[16], l[16];
#pragma unroll
        for (int j = 0; j < 16; j++) {
            h[j] = Th[(ts + j) * 72 + d];
            l[j] = Tl[(ts + j) * 72 + d];
        }
        u16* oh = Xhi + ((size_t)bh * D + d) * S + t0 + ts;
        u16* ol = Xlo + ((size_t)bh * D + d) * S + t0 + ts;
#pragma unroll
        for (int hf = 0; hf < 2; hf++) {
            uint4 ph, pl;
            ph.x = h[8*hf+0] | ((unsigned)h[8*hf+1] << 16);
            ph.y = h[8*hf+2] | ((unsigned)h[8*hf+3] << 16);
            ph.z = h[8*hf+4] | ((unsigned)h[8*hf+5] << 16);
            ph.w = h[8*hf+6] | ((unsigned)h[8*hf+7] << 16);
            pl.x = l[8*hf+0] | ((unsigned)l[8*hf+1] << 16);
            pl.y = l[8*hf+2] | ((unsigned)l[8*hf+3] << 16);
            pl.z = l[8*hf+4] | ((unsigned)l[8*hf+5] << 16);
            pl.w = l[8*hf+6] | ((unsigned)l[8*hf+7] << 16);
            *(uint4*)(oh + hf * 8) = ph;
            *(uint4*)(ol + hf * 8) = pl;
        }
    }
}

// ---------------------------------------------------------------------------
// K1/K3: C[1024 x 64] = A[1024 x 1024](fp32, split on the fly) @ B^T(pre-split)
// SPLIT_OUT: emit C as bf16 hi/lo pair (for M2), else fp32.
// Block 256 = 4 waves; block tile 128x64; wave tile 64x32; K-tile 64.
// ---------------------------------------------------------------------------
template <bool SPLIT_OUT>
__global__ __launch_bounds__(256) void gemm_split(
        const float* __restrict__ A, const u16* __restrict__ Bhg,
        const u16* __restrict__ Blg, float* __restrict__ Cf,
        u16* __restrict__ Ch, u16* __restrict__ Cl) {
    const int bh = blockIdx.y, mblk = blockIdx.x * 128, tid = threadIdx.x;
    const int lane = tid & 63, wave = tid >> 6;
    const int q = lane >> 4, r = lane & 15;
    const int wy = wave >> 1, wx = wave & 1;

    __shared__ u16 Ah[128 * 72], Al[128 * 72];
    __shared__ u16 Bsh[64 * 72], Bsl[64 * 72];

    const float* Ab = A + (size_t)bh * S * S + (size_t)mblk * S;
    const u16* Bhb = Bhg + (size_t)bh * D * S;
    const u16* Blb = Blg + (size_t)bh * D * S;

    f32x4 acc[4][2];
#pragma unroll
    for (int mt = 0; mt < 4; mt++)
#pragma unroll
        for (int nt = 0; nt < 2; nt++) acc[mt][nt] = 0.0f;

    const int arow = tid >> 3, aseg = tid & 7;  // A stage: rows arow+32i, k aseg*8..+7
    const int brow = tid >> 2, bseg = tid & 3;  // B stage: row brow, k bseg*16..+15

    float4 pa[4][2];
    uint4 pbh[2], pbl[2];

    auto prefetch = [&](int k0) {
#pragma unroll
        for (int i = 0; i < 4; i++) {
            const float* p = Ab + (size_t)(arow + 32 * i) * S + k0 + aseg * 8;
            pa[i][0] = *(const float4*)p;
            pa[i][1] = *(const float4*)(p + 4);
        }
        const u16* ph = Bhb + (size_t)brow * S + k0 + bseg * 16;
        const u16* pl = Blb + (size_t)brow * S + k0 + bseg * 16;
        pbh[0] = *(const uint4*)ph; pbh[1] = *(const uint4*)(ph + 8);
        pbl[0] = *(const uint4*)pl; pbl[1] = *(const uint4*)(pl + 8);
    };

    prefetch(0);
    for (int t = 0; t < 16; t++) {
        if (t) __syncthreads();
        // convert + stage A (hi/lo)
#pragma unroll
        for (int i = 0; i < 4; i++) {
            u16 h[8], l[8];
            float* pv = (float*)&pa[i][0];
#pragma unroll
            for (int j = 0; j < 8; j++) split2(pv[j], h[j], l[j]);
            uint4 ph, pl;
            ph.x = h[0] | ((unsigned)h[1] << 16); ph.y = h[2] | ((unsigned)h[3] << 16);
            ph.z = h[4] | ((unsigned)h[5] << 16); ph.w = h[6] | ((unsigned)h[7] << 16);
            pl.x = l[0] | ((unsigned)l[1] << 16); pl.y = l[2] | ((unsigned)l[3] << 16);
            pl.z = l[4] | ((unsigned)l[5] << 16); pl.w = l[6] | ((unsigned)l[7] << 16);
            *(uint4*)&Ah[(arow + 32 * i) * 72 + aseg * 8] = ph;
            *(uint4*)&Al[(arow + 32 * i) * 72 + aseg * 8] = pl;
        }
        // stage B (already bf16 in global)
        *(uint4*)&Bsh[brow * 72 + bseg * 16]     = pbh[0];
        *(uint4*)&Bsh[brow * 72 + bseg * 16 + 8] = pbh[1];
        *(uint4*)&Bsl[brow * 72 + bseg * 16]     = pbl[0];
        *(uint4*)&Bsl[brow * 72 + bseg * 16 + 8] = pbl[1];
        __syncthreads();
        if (t < 15) prefetch((t + 1) * 64);
#pragma unroll
        for (int kk = 0; kk < 2; kk++) {
            s16x8 afh[4], afl[4], bfh[2], bfl[2];
#pragma unroll
            for (int mt = 0; mt < 4; mt++) {
                const int row = wy * 64 + mt * 16 + r;
                afh[mt] = *(const s16x8*)&Ah[row * 72 + kk * 32 + q * 8];
                afl[mt] = *(const s16x8*)&Al[row * 72 + kk * 32 + q * 8];
            }
#pragma unroll
            for (int nt = 0; nt < 2; nt++) {
                const int col = wx * 32 + nt * 16 + r;
                bfh[nt] = *(const s16x8*)&Bsh[col * 72 + kk * 32 + q * 8];
                bfl[nt] = *(const s16x8*)&Bsl[col * 72 + kk * 32 + q * 8];
            }
#pragma unroll
            for (int mt = 0; mt < 4; mt++)
#pragma unroll
                for (int nt = 0; nt < 2; nt++) {
                    acc[mt][nt] = __builtin_amdgcn_mfma_f32_16x16x32_bf16(afh[mt], bfh[nt], acc[mt][nt], 0, 0, 0);
                    acc[mt][nt] = __builtin_amdgcn_mfma_f32_16x16x32_bf16(afh[mt], bfl[nt], acc[mt][nt], 0, 0, 0);
                    acc[mt][nt] = __builtin_amdgcn_mfma_f32_16x16x32_bf16(afl[mt], bfh[nt], acc[mt][nt], 0, 0, 0);
                }
        }
    }
    // epilogue: C row m = quad*4+reg, col n = lane&15 (verified mapping)
#pragma unroll
    for (int mt = 0; mt < 4; mt++)
#pragma unroll
        for (int nt = 0; nt < 2; nt++)
#pragma unroll
            for (int i = 0; i < 4; i++) {
                const int m = mblk + wy * 64 + mt * 16 + q * 4 + i;
                const int n = wx * 32 + nt * 16 + r;
                const float v = acc[mt][nt][i];
                if (SPLIT_OUT) {
                    u16 h, l;
                    split2(v, h, l);
                    Ch[((size_t)bh * S + m) * D + n] = h;
                    Cl[((size_t)bh * S + m) * D + n] = l;
                } else {
                    Cf[((size_t)bh * S + m) * D + n] = v;
                }
            }
}

// ---------------------------------------------------------------------------
// K2: logits = scale*Q @ M2^T via MFMA (K=64), softmax on C-fragments, write attn.
// Block 256 = 4 waves; s-tile 16, wave w covers u in [w*256, w*256+256).
// ---------------------------------------------------------------------------
__global__ __launch_bounds__(256) void logits_softmax_mfma(
        const float* __restrict__ Q, const u16* __restrict__ M2h,
        const u16* __restrict__ M2l, float* __restrict__ attn) {
    const int bh = blockIdx.y, s0 = blockIdx.x * 16, tid = threadIdx.x;
    const int w = tid >> 6, lane = tid & 63, q = lane >> 4, r = lane & 15;
    __shared__ u16 Qh[16 * 72], Ql[16 * 72];
    __shared__ float Lmx[4][16], Lsm[4][16];
    {   // stage Q row-tile, scale folded, split
        const int row = tid >> 4, c4 = (tid & 15) * 4;
        float4 v = *(const float4*)&Q[((size_t)bh * S + s0 + row) * D + c4];
        u16 h[4], l[4];
        split2(v.x * SCALE, h[0], l[0]);
        split2(v.y * SCALE, h[1], l[1]);
        split2(v.z * SCALE, h[2], l[2]);
        split2(v.w * SCALE, h[3], l[3]);
        uint2 ph, pl;
        ph.x = h[0] | ((unsigned)h[1] << 16); ph.y = h[2] | ((unsigned)h[3] << 16);
        pl.x = l[0] | ((unsigned)l[1] << 16); pl.y = l[2] | ((unsigned)l[3] << 16);
        *(uint2*)&Qh[row * 72 + c4] = ph;
        *(uint2*)&Ql[row * 72 + c4] = pl;
    }
    __syncthreads();
    s16x8 aq[2][2];
#pragma unroll
    for (int kk = 0; kk < 2; kk++) {
        aq[kk][0] = *(const s16x8*)&Qh[r * 72 + kk * 32 + q * 8];
        aq[kk][1] = *(const s16x8*)&Ql[r * 72 + kk * 32 + q * 8];
    }
    f32x4 acc[16];
#pragma unroll
    for (int nt = 0; nt < 16; nt++) acc[nt] = 0.0f;
    const u16* Bh = M2h + (size_t)bh * S * D;
    const u16* Bl = M2l + (size_t)bh * S * D;
#pragma unroll 4
    for (int nt = 0; nt < 16; nt++) {
        const int u = w * 256 + nt * 16 + r;
#pragma unroll
        for (int kk = 0; kk < 2; kk++) {
            s16x8 bh8 = *(const s16x8*)&Bh[(size_t)u * D + kk * 32 + q * 8];
            s16x8 bl8 = *(const s16x8*)&Bl[(size_t)u * D + kk * 32 + q * 8];
            acc[nt] = __builtin_amdgcn_mfma_f32_16x16x32_bf16(aq[kk][0], bh8, acc[nt], 0, 0, 0);
            acc[nt] = __builtin_amdgcn_mfma_f32_16x16x32_bf16(aq[kk][0], bl8, acc[nt], 0, 0, 0);
            acc[nt] = __builtin_amdgcn_mfma_f32_16x16x32_bf16(aq[kk][1], bh8, acc[nt], 0, 0, 0);
        }
    }
    // frag softmax: row (q*4+i) spans 16 lanes (r) x 16 nt
    float lmax[4], lsum[4];
#pragma unroll
    for (int i = 0; i < 4; i++) {
        float m = -3.0e38f;
#pragma unroll
        for (int nt = 0; nt < 16; nt++) m = fmaxf(m, acc[nt][i]);
#pragma unroll
        for (int off = 8; off >= 1; off >>= 1) m = fmaxf(m, __shfl_xor(m, off));
        lmax[i] = m;
        float s = 0.f;
#pragma unroll
        for (int nt = 0; nt < 16; nt++) {
            float e = __expf(acc[nt][i] - m);
            acc[nt][i] = e;
            s += e;
        }
#pragma unroll
        for (int off = 8; off >= 1; off >>= 1) s += __shfl_xor(s, off);
        lsum[i] = s;
    }
    if (r == 0) {
#pragma unroll
        for (int i = 0; i < 4; i++) {
            Lmx[w][q * 4 + i] = lmax[i];
            Lsm[w][q * 4 + i] = lsum[i];
        }
    }
    __syncthreads();
    float scl[4];
#pragma unroll
    for (int i = 0; i < 4; i++) {
        const int row = q * 4 + i;
        float gmax = fmaxf(fmaxf(Lmx[0][row], Lmx[1][row]), fmaxf(Lmx[2][row], Lmx[3][row]));
        float gsum = Lsm[0][row] * __expf(Lmx[0][row] - gmax)
                   + Lsm[1][row] * __expf(Lmx[1][row] - gmax)
                   + Lsm[2][row] * __expf(Lmx[2][row] - gmax)
                   + Lsm[3][row] * __expf(Lmx[3][row] - gmax);
        scl[i] = __expf(lmax[i] - gmax) / gsum;
    }
    float* out = attn + ((size_t)bh * S + s0) * S;
#pragma unroll
    for (int nt = 0; nt < 16; nt++)
#pragma unroll
        for (int i = 0; i < 4; i++)
            out[(size_t)(q * 4 + i) * S + w * 256 + nt * 16 + r] = acc[nt][i] * scl[i];
}

extern "C" void kernel_launch(void* const* d_in, const int* in_sizes, int n_in,
                              void* d_out, int out_size, void* d_ws, size_t ws_size,
                              hipStream_t stream) {
    const float* Q    = (const float*)d_in[0];
    const float* K    = (const float*)d_in[1];
    const float* V    = (const float*)d_in[2];
    const float* mask = (const float*)d_in[3];
    float* context = (float*)d_out;
    float* attn    = (float*)d_out + (size_t)BH * S * D;

    const size_t N = (size_t)BH * S * D;  // 4.19M elems per split array
    u16* M2h = (u16*)d_ws;
    u16* M2l = M2h + N;
    u16* Khi = M2l + N;
    u16* Klo = Khi + N;
    u16* Vhi = Klo + N;
    u16* Vlo = Vhi + N;   // total ws: 6*8.39MB = 50.3 MB

    split_transpose<<<dim3(16, BH, 2), 256, 0, stream>>>(K, V, Khi, Klo, Vhi, Vlo);
    gemm_split<true><<<dim3(8, BH), 256, 0, stream>>>(mask, Khi, Klo, nullptr, M2h, M2l);
    logits_softmax_mfma<<<dim3(64, BH), 256, 0, stream>>>(Q, M2h, M2l, attn);
    gemm_split<false><<<dim3(8, BH), 256, 0, stream>>>(attn, Vhi, Vlo, context, nullptr, nullptr);
}

// Round 3
// 932.123 us; speedup vs baseline: 1.0337x; 1.0337x over previous
//
#include <hip/hip_runtime.h>

// B=4,H=16 (BH=64), S=1024, D=64, fp32 in/out.
//   M2[u][d]   = sum_t mask[u][t] K[t][d]          (reassociated mask GEMM)
//   logits[s,u]= scale * sum_d Q[s][d] M2[u][d]
//   attn       = softmax(logits); context = attn @ V
// Split-fp32 bf16 MFMA: x = hi + lo, a*b ~= ah*bh + ah*bl + al*bh.
// R3: all global I/O coalesced. M2 lives in packed MFMA-B-fragment order.

#define S 1024
#define D 64
#define BH 64
#define SCALE 0.125f

typedef short s16x8 __attribute__((ext_vector_type(8)));
typedef float f32x4 __attribute__((ext_vector_type(4)));
typedef unsigned short u16;

__device__ __forceinline__ void split2(float x, u16& h, u16& l) {
    unsigned u = __float_as_uint(x);
    h = (u16)(u >> 16);
    float xh = __uint_as_float(u & 0xFFFF0000u);
    l = (u16)(__float_as_uint(x - xh) >> 16);
}

// packed M2 fragment index (element granularity = 8 u16 per slot)
__device__ __forceinline__ size_t m2idx(int bh, int ublk, int kk, int q, int r) {
    return (((((size_t)bh * 64 + ublk) * 2 + kk) * 4 + q) * 16 + r) * 8;
}

// ---------------------------------------------------------------------------
// K0: split K and V to bf16 hi/lo, transposed to [bh][d][t] (B-operand layout)
// ---------------------------------------------------------------------------
__global__ __launch_bounds__(256) void split_transpose(
        const float* __restrict__ Kin, const float* __restrict__ Vin,
        u16* __restrict__ Khi, u16* __restrict__ Klo,
        u16* __restrict__ Vhi, u16* __restrict__ Vlo) {
    const float* X = blockIdx.z ? Vin : Kin;
    u16* Xhi = blockIdx.z ? Vhi : Khi;
    u16* Xlo = blockIdx.z ? Vlo : Klo;
    const int bh = blockIdx.y, t0 = blockIdx.x * 64, tid = threadIdx.x;
    __shared__ u16 Th[64 * 72], Tl[64 * 72];
    {
        const int tr = tid >> 2, ds = (tid & 3) * 16;
        const float* src = X + ((size_t)bh * S + t0 + tr) * D + ds;
        u16 h[16], l[16];
#pragma unroll
        for (int j = 0; j < 4; j++) {
            float4 v = *(const float4*)(src + j * 4);
            split2(v.x, h[4 * j + 0], l[4 * j + 0]);
            split2(v.y, h[4 * j + 1], l[4 * j + 1]);
            split2(v.z, h[4 * j + 2], l[4 * j + 2]);
            split2(v.w, h[4 * j + 3], l[4 * j + 3]);
        }
#pragma unroll
        for (int hf = 0; hf < 2; hf++) {
            uint4 ph, pl;
            ph.x = h[8*hf+0] | ((unsigned)h[8*hf+1] << 16);
            ph.y = h[8*hf+2] | ((unsigned)h[8*hf+3] << 16);
            ph.z = h[8*hf+4] | ((unsigned)h[8*hf+5] << 16);
            ph.w = h[8*hf+6] | ((unsigned)h[8*hf+7] << 16);
            pl.x = l[8*hf+0] | ((unsigned)l[8*hf+1] << 16);
            pl.y = l[8*hf+2] | ((unsigned)l[8*hf+3] << 16);
            pl.z = l[8*hf+4] | ((unsigned)l[8*hf+5] << 16);
            pl.w = l[8*hf+6] | ((unsigned)l[8*hf+7] << 16);
            *(uint4*)&Th[tr * 72 + ds + hf * 8] = ph;
            *(uint4*)&Tl[tr * 72 + ds + hf * 8] = pl;
        }
    }
    __syncthreads();
    {
        const int d = tid >> 2, ts = (tid & 3) * 16;
        u16 h[16], l[16];
#pragma unroll
        for (int j = 0; j < 16; j++) {
            h[j] = Th[(ts + j) * 72 + d];
            l[j] = Tl[(ts + j) * 72 + d];
        }
        u16* oh = Xhi + ((size_t)bh * D + d) * S + t0 + ts;
        u16* ol = Xlo + ((size_t)bh * D + d) * S + t0 + ts;
#pragma unroll
        for (int hf = 0; hf < 2; hf++) {
            uint4 ph, pl;
            ph.x = h[8*hf+0] | ((unsigned)h[8*hf+1] << 16);
            ph.y = h[8*hf+2] | ((unsigned)h[8*hf+3] << 16);
            ph.z = h[8*hf+4] | ((unsigned)h[8*hf+5] << 16);
            ph.w = h[8*hf+6] | ((unsigned)h[8*hf+7] << 16);
            pl.x = l[8*hf+0] | ((unsigned)l[8*hf+1] << 16);
            pl.y = l[8*hf+2] | ((unsigned)l[8*hf+3] << 16);
            pl.z = l[8*hf+4] | ((unsigned)l[8*hf+5] << 16);
            pl.w = l[8*hf+6] | ((unsigned)l[8*hf+7] << 16);
            *(uint4*)(oh + hf * 8) = ph;
            *(uint4*)(ol + hf * 8) = pl;
        }
    }
}

// ---------------------------------------------------------------------------
// K1/K3: C[1024 x 64] = A[1024x1024](fp32, split on fly) @ B^T(pre-split)
// SPLIT_OUT: emit C as packed bf16 M2 fragments; else fp32 row-major.
// Block 256 = 4 waves; block tile 128x64; K-tile 64.
// ---------------------------------------------------------------------------
template <bool SPLIT_OUT>
__global__ __launch_bounds__(256) void gemm_split(
        const float* __restrict__ A, const u16* __restrict__ Bhg,
        const u16* __restrict__ Blg, float* __restrict__ Cf,
        u16* __restrict__ Ch, u16* __restrict__ Cl) {
    const int bh = blockIdx.y, mblk = blockIdx.x * 128, tid = threadIdx.x;
    const int lane = tid & 63, wave = tid >> 6;
    const int q = lane >> 4, r = lane & 15;
    const int wy = wave >> 1, wx = wave & 1;

    __shared__ alignas(16) char smem[55296];
    u16* Ah  = (u16*)smem;            // [128][72]
    u16* Al  = Ah + 128 * 72;
    u16* Bsh = Al + 128 * 72;         // [64][72]
    u16* Bsl = Bsh + 64 * 72;

    const float* Ab = A + (size_t)bh * S * S + (size_t)mblk * S;
    const u16* Bhb = Bhg + (size_t)bh * D * S;
    const u16* Blb = Blg + (size_t)bh * D * S;

    f32x4 acc[4][2];
#pragma unroll
    for (int mt = 0; mt < 4; mt++)
#pragma unroll
        for (int nt = 0; nt < 2; nt++) acc[mt][nt] = 0.0f;

    const int arow = tid >> 3, aseg = tid & 7;
    const int brow = tid >> 2, bseg = tid & 3;

    float4 pa[4][2];
    uint4 pbh[2], pbl[2];

    auto prefetch = [&](int k0) {
#pragma unroll
        for (int i = 0; i < 4; i++) {
            const float* p = Ab + (size_t)(arow + 32 * i) * S + k0 + aseg * 8;
            pa[i][0] = *(const float4*)p;
            pa[i][1] = *(const float4*)(p + 4);
        }
        const u16* ph = Bhb + (size_t)brow * S + k0 + bseg * 16;
        const u16* pl = Blb + (size_t)brow * S + k0 + bseg * 16;
        pbh[0] = *(const uint4*)ph; pbh[1] = *(const uint4*)(ph + 8);
        pbl[0] = *(const uint4*)pl; pbl[1] = *(const uint4*)(pl + 8);
    };

    prefetch(0);
    for (int t = 0; t < 16; t++) {
        if (t) __syncthreads();
#pragma unroll
        for (int i = 0; i < 4; i++) {
            u16 h[8], l[8];
            float* pv = (float*)&pa[i][0];
#pragma unroll
            for (int j = 0; j < 8; j++) split2(pv[j], h[j], l[j]);
            uint4 ph, pl;
            ph.x = h[0] | ((unsigned)h[1] << 16); ph.y = h[2] | ((unsigned)h[3] << 16);
            ph.z = h[4] | ((unsigned)h[5] << 16); ph.w = h[6] | ((unsigned)h[7] << 16);
            pl.x = l[0] | ((unsigned)l[1] << 16); pl.y = l[2] | ((unsigned)l[3] << 16);
            pl.z = l[4] | ((unsigned)l[5] << 16); pl.w = l[6] | ((unsigned)l[7] << 16);
            *(uint4*)&Ah[(arow + 32 * i) * 72 + aseg * 8] = ph;
            *(uint4*)&Al[(arow + 32 * i) * 72 + aseg * 8] = pl;
        }
        *(uint4*)&Bsh[brow * 72 + bseg * 16]     = pbh[0];
        *(uint4*)&Bsh[brow * 72 + bseg * 16 + 8] = pbh[1];
        *(uint4*)&Bsl[brow * 72 + bseg * 16]     = pbl[0];
        *(uint4*)&Bsl[brow * 72 + bseg * 16 + 8] = pbl[1];
        __syncthreads();
        if (t < 15) prefetch((t + 1) * 64);
#pragma unroll
        for (int kk = 0; kk < 2; kk++) {
            s16x8 afh[4], afl[4], bfh[2], bfl[2];
#pragma unroll
            for (int mt = 0; mt < 4; mt++) {
                const int row = wy * 64 + mt * 16 + r;
                afh[mt] = *(const s16x8*)&Ah[row * 72 + kk * 32 + q * 8];
                afl[mt] = *(const s16x8*)&Al[row * 72 + kk * 32 + q * 8];
            }
#pragma unroll
            for (int nt = 0; nt < 2; nt++) {
                const int col = wx * 32 + nt * 16 + r;
                bfh[nt] = *(const s16x8*)&Bsh[col * 72 + kk * 32 + q * 8];
                bfl[nt] = *(const s16x8*)&Bsl[col * 72 + kk * 32 + q * 8];
            }
#pragma unroll
            for (int mt = 0; mt < 4; mt++)
#pragma unroll
                for (int nt = 0; nt < 2; nt++) {
                    acc[mt][nt] = __builtin_amdgcn_mfma_f32_16x16x32_bf16(afh[mt], bfh[nt], acc[mt][nt], 0, 0, 0);
                    acc[mt][nt] = __builtin_amdgcn_mfma_f32_16x16x32_bf16(afh[mt], bfl[nt], acc[mt][nt], 0, 0, 0);
                    acc[mt][nt] = __builtin_amdgcn_mfma_f32_16x16x32_bf16(afl[mt], bfh[nt], acc[mt][nt], 0, 0, 0);
                }
        }
    }

    // ---- epilogue: C frags -> LDS [128][68] fp32 -> coalesced global ----
    __syncthreads();
    float* Cs = (float*)smem;  // [128][68], 34816 B (fits in 55296)
#pragma unroll
    for (int mt = 0; mt < 4; mt++)
#pragma unroll
        for (int nt = 0; nt < 2; nt++)
#pragma unroll
            for (int i = 0; i < 4; i++)
                Cs[(wy * 64 + mt * 16 + q * 4 + i) * 68 + wx * 32 + nt * 16 + r] = acc[mt][nt][i];
    __syncthreads();

    if (SPLIT_OUT) {
#pragma unroll
        for (int it = 0; it < 4; it++) {
            const int sidx = tid + 256 * it;          // 0..1023 packed slots
            const int rr = sidx & 15, qq = (sidx >> 4) & 3;
            const int kk = (sidx >> 6) & 1, ub = sidx >> 7;  // 0..7
            const int ul = ub * 16 + rr, d0 = kk * 32 + qq * 8;
            u16 h[8], l[8];
#pragma unroll
            for (int j = 0; j < 8; j++) split2(Cs[ul * 68 + d0 + j], h[j], l[j]);
            uint4 ph, pl;
            ph.x = h[0] | ((unsigned)h[1] << 16); ph.y = h[2] | ((unsigned)h[3] << 16);
            ph.z = h[4] | ((unsigned)h[5] << 16); ph.w = h[6] | ((unsigned)h[7] << 16);
            pl.x = l[0] | ((unsigned)l[1] << 16); pl.y = l[2] | ((unsigned)l[3] << 16);
            pl.z = l[4] | ((unsigned)l[5] << 16); pl.w = l[6] | ((unsigned)l[7] << 16);
            const size_t off = m2idx(bh, (mblk >> 4) + ub, kk, qq, rr);
            *(uint4*)&Ch[off] = ph;
            *(uint4*)&Cl[off] = pl;
        }
    } else {
#pragma unroll
        for (int it = 0; it < 8; it++) {
            const int f = tid + 256 * it;             // float4 id 0..2047
            const int row = f >> 4, c4 = (f & 15) * 4;
            float4 v = *(const float4*)&Cs[row * 68 + c4];
            *(float4*)&Cf[((size_t)bh * S + mblk + row) * D + c4] = v;
        }
    }
}

// ---------------------------------------------------------------------------
// K2: logits = scale*Q @ M2^T (packed frags) via MFMA, softmax, coalesced attn.
// 1-D grid 4096, XCD swizzle: head -> fixed XCD slot, s-tiles consecutive.
// ---------------------------------------------------------------------------
__global__ __launch_bounds__(256) void logits_softmax_mfma(
        const float* __restrict__ Q, const u16* __restrict__ M2h,
        const u16* __restrict__ M2l, float* __restrict__ attn) {
    const int id = blockIdx.x;
    const int h  = (id & 7) + ((id >> 9) << 3);   // head: id%8 fixes XCD slot
    const int s0 = ((id >> 3) & 63) * 16;
    const int tid = threadIdx.x;
    const int w = tid >> 6, lane = tid & 63, q = lane >> 4, r = lane & 15;

    __shared__ u16 Qh[16 * 72], Ql[16 * 72];
    __shared__ float Lmx[4][16], Lsm[4][16];
    __shared__ alignas(16) float At[4][8][260];   // per-wave transpose buffer

    {
        const int row = tid >> 4, c4 = (tid & 15) * 4;
        float4 v = *(const float4*)&Q[((size_t)h * S + s0 + row) * D + c4];
        u16 hh[4], ll[4];
        split2(v.x * SCALE, hh[0], ll[0]);
        split2(v.y * SCALE, hh[1], ll[1]);
        split2(v.z * SCALE, hh[2], ll[2]);
        split2(v.w * SCALE, hh[3], ll[3]);
        uint2 ph, pl;
        ph.x = hh[0] | ((unsigned)hh[1] << 16); ph.y = hh[2] | ((unsigned)hh[3] << 16);
        pl.x = ll[0] | ((unsigned)ll[1] << 16); pl.y = ll[2] | ((unsigned)ll[3] << 16);
        *(uint2*)&Qh[row * 72 + c4] = ph;
        *(uint2*)&Ql[row * 72 + c4] = pl;
    }
    __syncthreads();
    s16x8 aq[2][2];
#pragma unroll
    for (int kk = 0; kk < 2; kk++) {
        aq[kk][0] = *(const s16x8*)&Qh[r * 72 + kk * 32 + q * 8];
        aq[kk][1] = *(const s16x8*)&Ql[r * 72 + kk * 32 + q * 8];
    }
    f32x4 acc[16];
#pragma unroll
    for (int nt = 0; nt < 16; nt++) acc[nt] = 0.0f;

#pragma unroll 4
    for (int nt = 0; nt < 16; nt++) {
        const int ublk = w * 16 + nt;
        const size_t o0 = m2idx(h, ublk, 0, q, r);
        const size_t o1 = m2idx(h, ublk, 1, q, r);
        s16x8 b0h = *(const s16x8*)&M2h[o0];
        s16x8 b0l = *(const s16x8*)&M2l[o0];
        s16x8 b1h = *(const s16x8*)&M2h[o1];
        s16x8 b1l = *(const s16x8*)&M2l[o1];
        acc[nt] = __builtin_amdgcn_mfma_f32_16x16x32_bf16(aq[0][0], b0h, acc[nt], 0, 0, 0);
        acc[nt] = __builtin_amdgcn_mfma_f32_16x16x32_bf16(aq[0][0], b0l, acc[nt], 0, 0, 0);
        acc[nt] = __builtin_amdgcn_mfma_f32_16x16x32_bf16(aq[0][1], b0h, acc[nt], 0, 0, 0);
        acc[nt] = __builtin_amdgcn_mfma_f32_16x16x32_bf16(aq[1][0], b1h, acc[nt], 0, 0, 0);
        acc[nt] = __builtin_amdgcn_mfma_f32_16x16x32_bf16(aq[1][0], b1l, acc[nt], 0, 0, 0);
        acc[nt] = __builtin_amdgcn_mfma_f32_16x16x32_bf16(aq[1][1], b1h, acc[nt], 0, 0, 0);
    }

    float lmax[4], lsum[4];
#pragma unroll
    for (int i = 0; i < 4; i++) {
        float m = -3.0e38f;
#pragma unroll
        for (int nt = 0; nt < 16; nt++) m = fmaxf(m, acc[nt][i]);
#pragma unroll
        for (int off = 8; off >= 1; off >>= 1) m = fmaxf(m, __shfl_xor(m, off));
        lmax[i] = m;
        float ssum = 0.f;
#pragma unroll
        for (int nt = 0; nt < 16; nt++) {
            float e = __expf(acc[nt][i] - m);
            acc[nt][i] = e;
            ssum += e;
        }
#pragma unroll
        for (int off = 8; off >= 1; off >>= 1) ssum += __shfl_xor(ssum, off);
        lsum[i] = ssum;
    }
    if (r == 0) {
#pragma unroll
        for (int i = 0; i < 4; i++) {
            Lmx[w][q * 4 + i] = lmax[i];
            Lsm[w][q * 4 + i] = lsum[i];
        }
    }
    __syncthreads();
    float scl[4];
#pragma unroll
    for (int i = 0; i < 4; i++) {
        const int row = q * 4 + i;
        float gmax = fmaxf(fmaxf(Lmx[0][row], Lmx[1][row]), fmaxf(Lmx[2][row], Lmx[3][row]));
        float gsum = Lsm[0][row] * __expf(Lmx[0][row] - gmax)
                   + Lsm[1][row] * __expf(Lmx[1][row] - gmax)
                   + Lsm[2][row] * __expf(Lmx[2][row] - gmax)
                   + Lsm[3][row] * __expf(Lmx[3][row] - gmax);
        scl[i] = __expf(lmax[i] - gmax) / gsum;
    }

    // coalesced attn write: two 8-row chunks through per-wave LDS transpose
    float* out = attn + ((size_t)h * S + s0) * S + w * 256;
#pragma unroll
    for (int c = 0; c < 2; c++) {
        if ((q >> 1) == c) {
#pragma unroll
            for (int nt = 0; nt < 16; nt++)
#pragma unroll
                for (int i = 0; i < 4; i++)
                    At[w][(q & 1) * 4 + i][nt * 16 + r] = acc[nt][i] * scl[i];
        }
        __syncthreads();
#pragma unroll
        for (int row = 0; row < 8; row++) {
            float4 v = *(const float4*)&At[w][row][lane * 4];
            *(float4*)&out[(size_t)(c * 8 + row) * S + lane * 4] = v;
        }
        __syncthreads();
    }
}

extern "C" void kernel_launch(void* const* d_in, const int* in_sizes, int n_in,
                              void* d_out, int out_size, void* d_ws, size_t ws_size,
                              hipStream_t stream) {
    const float* Q    = (const float*)d_in[0];
    const float* K    = (const float*)d_in[1];
    const float* V    = (const float*)d_in[2];
    const float* mask = (const float*)d_in[3];
    float* context = (float*)d_out;
    float* attn    = (float*)d_out + (size_t)BH * S * D;

    const size_t N = (size_t)BH * S * D;
    u16* M2h = (u16*)d_ws;
    u16* M2l = M2h + N;
    u16* Khi = M2l + N;
    u16* Klo = Khi + N;
    u16* Vhi = Klo + N;
    u16* Vlo = Vhi + N;   // 50.3 MB total

    split_transpose<<<dim3(16, BH, 2), 256, 0, stream>>>(K, V, Khi, Klo, Vhi, Vlo);
    gemm_split<true><<<dim3(8, BH), 256, 0, stream>>>(mask, Khi, Klo, nullptr, M2h, M2l);
    logits_softmax_mfma<<<4096, 256, 0, stream>>>(Q, M2h, M2l, attn);
    gemm_split<false><<<dim3(8, BH), 256, 0, stream>>>(attn, Vhi, Vlo, context, nullptr, nullptr);
}